// Round 8
// baseline (306.943 us; speedup 1.0000x reference)
//
#include <hip/hip_runtime.h>
#include <math.h>

#define BB 8
#define NN 4096
#define DIMc 256
#define HH 8
#define DH 64
#define INNERc 512

typedef unsigned short us;
typedef short s16x8 __attribute__((ext_vector_type(8)));   // 8 bf16 operand (4 VGPRs)
typedef float f32x4 __attribute__((ext_vector_type(4)));   // 16x16 C/D frag

static __device__ __forceinline__ us f2bf(float f) {
    union { float f; unsigned int u; } c; c.f = f;
    unsigned int u = c.u;
    return (us)((u + 0x7fffu + ((u >> 16) & 1u)) >> 16);   // RNE
}

// pack 2 floats -> 2 bf16 in one instruction (RNE). lo -> bits[15:0].
static __device__ __forceinline__ unsigned int pkbf(float lo, float hi) {
    unsigned int r;
    asm("v_cvt_pk_bf16_f32 %0, %1, %2" : "=v"(r) : "v"(lo), "v"(hi));
    return r;
}

#define MFMA16(a, b, c) __builtin_amdgcn_mfma_f32_16x16x32_bf16((a), (b), (c), 0, 0, 0)

// async 16B/lane global->LDS. LDS dest must be linear: base + lane*16.
static __device__ __forceinline__ void glds16(const us* g, us* l) {
    __builtin_amdgcn_global_load_lds(
        (const __attribute__((address_space(1))) void*)g,
        (__attribute__((address_space(3))) void*)l, 16, 0, 0);
}

// ---------------------------------------------------------------
// prep: ONE dispatch for all preprocessing:
//   [0,16384)     cast z / x -> bf16
//   [16384,16896) WqT   [16896,17920) WkvT   [17920,18432) WoutT
//   [18432,18688) dots = 0
//   [18688,20736) ropeZ   [20736,22784) ropeX
// ---------------------------------------------------------------
__global__ __launch_bounds__(256) void prep(
    const float* __restrict__ x, const float* __restrict__ z,
    const float* __restrict__ x_pos, const float* __restrict__ z_pos,
    const float* __restrict__ Wq, const float* __restrict__ Wkv,
    const float* __restrict__ Wout,
    us* __restrict__ x_bf, us* __restrict__ z_bf,
    us* __restrict__ WqT, us* __restrict__ WkvT, us* __restrict__ WoutT,
    float* __restrict__ dots, float4* __restrict__ ropeX, float4* __restrict__ ropeZ)
{
    const int bid = blockIdx.x, tid = threadIdx.x;
    if (bid < 16384) {                       // cast z / x (float4 -> 4x bf16)
        const int isX = bid >= 8192;
        const int idx = (bid - (isX ? 8192 : 0)) * 256 + tid;   // < 2097152
        float4 v = ((const float4*)(isX ? x : z))[idx];
        uint2 u;
        u.x = pkbf(v.x, v.y);
        u.y = pkbf(v.z, v.w);
        ((uint2*)(isX ? x_bf : z_bf))[idx] = u;
    } else if (bid < 16896) {                // WqT
        const int idx = (bid - 16384) * 256 + tid;   // < 131072
        const int r = idx >> 8, c = idx & 255;
        WqT[idx] = f2bf(Wq[(size_t)c * 512 + r]);
    } else if (bid < 17920) {                // WkvT
        const int idx = (bid - 16896) * 256 + tid;   // < 262144
        const int r = idx >> 8, c = idx & 255;
        WkvT[idx] = f2bf(Wkv[(size_t)c * 1024 + r]);
    } else if (bid < 18432) {                // WoutT
        const int idx = (bid - 17920) * 256 + tid;   // < 131072
        const int r = idx >> 9, c = idx & 511;
        WoutT[idx] = f2bf(Wout[(size_t)c * 256 + r]);
    } else if (bid < 18688) {                // dots = 0 (65536 float4)
        const int idx = (bid - 18432) * 256 + tid;
        ((float4*)dots)[idx] = float4{0.f, 0.f, 0.f, 0.f};
    } else {                                 // rope tables
        const int isZ = bid < 20736;
        const int idx = (bid - (isZ ? 18688 : 20736)) * 256 + tid;  // < 524288
        const int f = idx & 15, row = idx >> 4;                     // row = b*NN+n
        float invf = exp2f((float)f * -0.83048202f);   // 10000^(-f/16)
        const float* p = (isZ ? z_pos : x_pos) + (size_t)row * 2;
        float sx, cx, sy, cy;
        sincosf(p[0] * 64.f * invf, &sx, &cx);
        sincosf(p[1] * 64.f * invf, &sy, &cy);
        (isZ ? ropeZ : ropeX)[idx] = float4{cx, sx, cy, sy};
    }
}

// ---------------------------------------------------------------
// kvdots: fused. Per block (b, ntile, h):
//   GEMM 128n x [K_h(64) | V_h(64)] cols, K=256 (global_load_lds staging,
//   XOR-swizzled LDS) -> in-reg instance-norm + rotary(K, table from ropeZ)
//   -> K,V to LDS [64][128n] swizzled -> dots_h partial -> fp32 atomics.
// grid (x: b*32+ntile = 256, y: h = 8), 512 threads (8 waves).
// ---------------------------------------------------------------
__global__ __launch_bounds__(512) void kvdots(
    const us* __restrict__ zbf, const float4* __restrict__ ropeZ,
    const us* __restrict__ WkvT, float* __restrict__ dots)
{
    __shared__ __align__(16) char smem[65536];
    us* Abuf = (us*)smem;               // [128][64] us, swizzled granules (16KB)
    us* Bbuf = (us*)(smem + 16384);     // [128][64] us (16KB)
    us* Kl = (us*)(smem + 32768);       // [64 d][128 n] us, swizzled (16KB)
    us* Vl = (us*)(smem + 49152);       // [64 e][128 n] us, swizzled (16KB)

    const int tid = threadIdx.x;
    const int b  = blockIdx.x >> 5;
    const int r0 = (blockIdx.x & 31) * 128;
    const int h  = blockIdx.y;

    const int wave = tid >> 6, lane = tid & 63;
    const int lr = lane & 15, quad = lane >> 4;
    const int wrow = wave & 3;          // 32-row block of the 128 n rows
    const int wc   = wave >> 2;         // 0: K half, 1: V half

    const us* Asrc = zbf + ((size_t)b * NN + r0) * DIMc;
    const float4* rz = ropeZ + ((size_t)b * NN + r0) * 16;

    const int srow = lane >> 3;
    const int sq   = (lane & 7) ^ srow;

    f32x4 z4 = {0.f, 0.f, 0.f, 0.f};
    f32x4 acc[2][4];
    #pragma unroll
    for (int i = 0; i < 2; ++i)
        #pragma unroll
        for (int j = 0; j < 4; ++j) acc[i][j] = z4;

    for (int kc = 0; kc < 256; kc += 64) {
        #pragma unroll
        for (int k = 0; k < 4; ++k) {
            const int c = wave * 4 + k;          // 0..31: 16 A chunks, 16 B chunks
            if (c < 16) {
                const int row = c * 8 + srow;
                glds16(Asrc + (size_t)row * DIMc + kc + sq * 8,
                       Abuf + c * 512 + lane * 8);
            } else {
                const int brow = (c - 16) * 8 + srow;      // 0..127
                const int wrg = h * 64 + brow + ((brow & 64) ? 448 : 0);
                glds16(WkvT + (size_t)wrg * DIMc + kc + sq * 8,
                       Bbuf + (c - 16) * 512 + lane * 8);
            }
        }
        __syncthreads();
        #pragma unroll
        for (int ks = 0; ks < 64; ks += 32) {
            const int qb = (ks >> 3) + quad;     // logical granule wanted
            s16x8 a[2], bfr[4];
            #pragma unroll
            for (int i = 0; i < 2; ++i) {
                const int row = wrow * 32 + i * 16 + lr;
                a[i] = *(const s16x8*)(Abuf + row * 64 + ((qb ^ (row & 7)) << 3));
            }
            #pragma unroll
            for (int j = 0; j < 4; ++j) {
                const int brow = wc * 64 + j * 16 + lr;
                bfr[j] = *(const s16x8*)(Bbuf + brow * 64 + ((qb ^ (brow & 7)) << 3));
            }
            #pragma unroll
            for (int i = 0; i < 2; ++i)
                #pragma unroll
                for (int j = 0; j < 4; ++j)
                    acc[i][j] = MFMA16(a[i], bfr[j], acc[i][j]);
        }
        __syncthreads();
    }

    // epilogue: norm (+rotary for K from ropeZ) in regs -> Kl/Vl [64][128] swizzled
    us* KVl = wc ? Vl : Kl;
    #pragma unroll
    for (int i = 0; i < 2; ++i) {
        float mu_[4], rs_[4];
        #pragma unroll
        for (int r = 0; r < 4; ++r) {
            float s = acc[i][0][r] + acc[i][1][r] + acc[i][2][r] + acc[i][3][r];
            float q2 = acc[i][0][r] * acc[i][0][r] + acc[i][1][r] * acc[i][1][r]
                     + acc[i][2][r] * acc[i][2][r] + acc[i][3][r] * acc[i][3][r];
            s += __shfl_xor(s, 1);  q2 += __shfl_xor(q2, 1);
            s += __shfl_xor(s, 2);  q2 += __shfl_xor(q2, 2);
            s += __shfl_xor(s, 4);  q2 += __shfl_xor(q2, 4);
            s += __shfl_xor(s, 8);  q2 += __shfl_xor(q2, 8);
            float mu = s * (1.f / 64.f);
            float var = q2 * (1.f / 64.f) - mu * mu;
            mu_[r] = mu;
            rs_[r] = rsqrtf(var + 1e-5f);
        }
        float4 tb[4];
        if (wc == 0) {
            #pragma unroll
            for (int r = 0; r < 4; ++r)
                tb[r] = rz[(wrow * 32 + i * 16 + quad * 4 + r) * 16 + lr];
        }
        #pragma unroll
        for (int j = 0; j < 4; ++j) {
            float vv[4];
            #pragma unroll
            for (int r = 0; r < 4; ++r) {
                float v0 = (acc[i][j][r] - mu_[r]) * rs_[r];
                if (wc == 0) {
                    float v1 = (acc[i][j ^ 1][r] - mu_[r]) * rs_[r];
                    float cc = (j < 2) ? tb[r].x : tb[r].z;
                    float sn = (j < 2) ? tb[r].y : tb[r].w;
                    v0 = (j & 1) ? fmaf(v0, cc, v1 * sn) : fmaf(v0, cc, -(v1 * sn));
                }
                vv[r] = v0;
            }
            uint2 pk;
            pk.x = pkbf(vv[0], vv[1]);
            pk.y = pkbf(vv[2], vv[3]);
            const int d = j * 16 + lr;
            const int n = wrow * 32 + i * 16 + quad * 4;   // 4-aligned
            const int g = n >> 3, hs = (n >> 2) & 1;       // 16B granule, 8B half
            *(uint2*)((char*)KVl + d * 256 + ((g ^ (d & 15)) << 4) + hs * 8) = pk;
        }
    }
    __syncthreads();

    // dots_h partial: dots[d][e] += sum_{n in tile} K[n,d] * V[n,e]
    const int d0 = (wave & 3) * 16, e0 = (wave >> 2) * 32;
    f32x4 c2[2] = {z4, z4};
    #pragma unroll
    for (int kk = 0; kk < 128; kk += 32) {
        const int qg = (kk >> 3) + quad;
        const int da = d0 + lr;
        s16x8 a = *(const s16x8*)(Kl + da * 128 + ((qg ^ (da & 15)) << 3));
        #pragma unroll
        for (int j = 0; j < 2; ++j) {
            const int e = e0 + j * 16 + lr;
            s16x8 bb = *(const s16x8*)(Vl + e * 128 + ((qg ^ (e & 15)) << 3));
            c2[j] = MFMA16(a, bb, c2[j]);
        }
    }
    float* dp = dots + ((size_t)b * HH + h) * (DH * DH);
    #pragma unroll
    for (int j = 0; j < 2; ++j)
        #pragma unroll
        for (int r = 0; r < 4; ++r)
            atomicAdd(dp + (d0 + quad * 4 + r) * 64 + e0 + j * 16 + lr, c2[j][r]);
}

// ---------------------------------------------------------------
// mbuild: Mt[b][o][h*64+d] = sum_e dots[b,h][d][e]/N * WoutT[o][h*64+e]
// grid: 64 blocks = (b,h); 256 threads (4 waves, each 64 o-rows).
// ---------------------------------------------------------------
__global__ __launch_bounds__(256) void mbuild(
    const float* __restrict__ dots, const us* __restrict__ WoutT,
    us* __restrict__ Mt)
{
    __shared__ __align__(16) us dlds[64 * 72];   // dots_h bf16, row d, padded
    const int bh = blockIdx.x;
    const int b = bh >> 3, h = bh & 7;
    const int tid = threadIdx.x;

    for (int i = tid; i < 4096; i += 256) {
        int d = i >> 6, e = i & 63;
        dlds[d * 72 + e] = f2bf(dots[(size_t)bh * 4096 + i] * (1.f / (float)NN));
    }
    __syncthreads();

    const int wave = tid >> 6, lane = tid & 63;
    const int lr = lane & 15, quad = lane >> 4;
    const int o0 = wave * 64;

    f32x4 z4 = {0.f, 0.f, 0.f, 0.f};
    f32x4 c[4][4];
    #pragma unroll
    for (int i = 0; i < 4; ++i)
        #pragma unroll
        for (int j = 0; j < 4; ++j) c[i][j] = z4;

    #pragma unroll
    for (int ks = 0; ks < 64; ks += 32) {
        s16x8 a[4], bfr[4];
        #pragma unroll
        for (int i = 0; i < 4; ++i)
            a[i] = *(const s16x8*)(WoutT + (size_t)(o0 + i * 16 + lr) * INNERc + h * 64 + ks + quad * 8);
        #pragma unroll
        for (int j = 0; j < 4; ++j)
            bfr[j] = *(const s16x8*)(dlds + (j * 16 + lr) * 72 + ks + quad * 8);
        #pragma unroll
        for (int i = 0; i < 4; ++i)
            #pragma unroll
            for (int j = 0; j < 4; ++j)
                c[i][j] = MFMA16(a[i], bfr[j], c[i][j]);
    }

    us* Mb = Mt + (size_t)b * (DIMc * INNERc);   // [256 o][512 he]
    #pragma unroll
    for (int i = 0; i < 4; ++i)
        #pragma unroll
        for (int j = 0; j < 4; ++j) {
            const int d = j * 16 + lr;
            #pragma unroll
            for (int r = 0; r < 4; ++r)
                Mb[(size_t)(o0 + i * 16 + quad * 4 + r) * INNERc + h * 64 + d] = f2bf(c[i][j][r]);
        }
}

// ---------------------------------------------------------------
// qout_gemm v4: 32-row n-tiles, 256 threads (4 waves), grid 1024 = 4 blocks/CU,
// __launch_bounds__(256,4) caps VGPR at 128 -> 16 waves/CU.
// Per chunk ch (heads ch*4..ch*4+3): q = x@Wq (32n x 256he, K=256) via
// glds16 staging (XOR-swizzled) -> rotary (from ropeX) -> qlds [32][256]
// swizzled (aliases staging) -> acc2 += Mt[b][:,chunk] x q^T (K=256).
// Epilogue: out[n][o] = acc2 + bout[o].
// LDS: staging A 4K + B 32K (qlds 16K aliases) = 36864 B.
// ---------------------------------------------------------------
__global__ __launch_bounds__(256, 4) void qout_gemm(
    const us* __restrict__ xbf, const float4* __restrict__ ropeX,
    const us* __restrict__ WqT, const us* __restrict__ Mt,
    const float* __restrict__ bout, float* __restrict__ out)
{
    __shared__ __align__(16) char smem[36864];
    us* Abuf = (us*)smem;                    // [32][64] granule-swizzled (4 KB)
    us* Bbuf = (us*)(smem + 4096);           // [256][64] granule-swizzled (32 KB)
    us* qlds = (us*)smem;                    // alias: [32 n][256 he] swizzled (16 KB)

    const int tid = threadIdx.x;
    const int b  = blockIdx.x >> 7;
    const int n0 = (blockIdx.x & 127) * 32;
    const int wave = tid >> 6, lane = tid & 63;
    const int lr = lane & 15, quad = lane >> 4;
    const int srow = lane >> 3;
    const int sq   = (lane & 7) ^ srow;

    const us* Asrc = xbf + ((size_t)b * NN + n0) * DIMc;
    const float4* rx = ropeX + ((size_t)b * NN + n0) * 16;
    const us* Mb = Mt + (size_t)b * (DIMc * INNERc);

    f32x4 z4 = {0.f, 0.f, 0.f, 0.f};
    f32x4 acc2[4][2];                        // [o-frag][n-frag]
    #pragma unroll
    for (int i = 0; i < 4; ++i)
        #pragma unroll
        for (int j = 0; j < 2; ++j) acc2[i][j] = z4;

    for (int ch = 0; ch < 2; ++ch) {
        f32x4 acc[2][4];                     // [n-frag][he-frag]
        #pragma unroll
        for (int i = 0; i < 2; ++i)
            #pragma unroll
            for (int j = 0; j < 4; ++j) acc[i][j] = z4;

        for (int kc = 0; kc < 256; kc += 64) {
            // 36 chunks of 1024B (A: 4, B: 32), 9 per wave
            #pragma unroll
            for (int k = 0; k < 9; ++k) {
                const int c = wave * 9 + k;
                if (c < 4) {
                    const int row = c * 8 + srow;
                    glds16(Asrc + (size_t)row * DIMc + kc + sq * 8,
                           Abuf + c * 512 + lane * 8);
                } else {
                    const int cb = c - 4;
                    const int grow = ch * 256 + cb * 8 + srow;
                    glds16(WqT + (size_t)grow * DIMc + kc + sq * 8,
                           Bbuf + cb * 512 + lane * 8);
                }
            }
            __syncthreads();
            #pragma unroll
            for (int ks = 0; ks < 64; ks += 32) {
                const int qb = (ks >> 3) + quad;
                s16x8 a[2], bfr[4];
                #pragma unroll
                for (int i = 0; i < 2; ++i) {
                    const int row = i * 16 + lr;
                    a[i] = *(const s16x8*)(Abuf + row * 64 + ((qb ^ (row & 7)) << 3));
                }
                #pragma unroll
                for (int j = 0; j < 4; ++j) {
                    const int brow = wave * 64 + j * 16 + lr;
                    bfr[j] = *(const s16x8*)(Bbuf + brow * 64 + ((qb ^ (brow & 7)) << 3));
                }
                #pragma unroll
                for (int i = 0; i < 2; ++i)
                    #pragma unroll
                    for (int j = 0; j < 4; ++j)
                        acc[i][j] = MFMA16(a[i], bfr[j], acc[i][j]);
            }
            __syncthreads();
        }

        // rotary in regs (table from ropeX) -> qlds [32][256] swizzled
        #pragma unroll
        for (int i = 0; i < 2; ++i) {
            float4 tb[4];
            #pragma unroll
            for (int r = 0; r < 4; ++r)
                tb[r] = rx[(i * 16 + quad * 4 + r) * 16 + lr];
            #pragma unroll
            for (int j = 0; j < 4; ++j) {
                const int col = wave * 64 + j * 16 + lr;
                #pragma unroll
                for (int r = 0; r < 4; ++r) {
                    const int row = i * 16 + quad * 4 + r;
                    float v0 = acc[i][j][r];
                    float v1 = acc[i][j ^ 1][r];
                    float cc = (j < 2) ? tb[r].x : tb[r].z;
                    float sn = (j < 2) ? tb[r].y : tb[r].w;
                    float val = (j & 1) ? fmaf(v0, cc, v1 * sn) : fmaf(v0, cc, -(v1 * sn));
                    *(us*)((char*)qlds + row * 512 + ((col * 2) ^ ((row & 7) << 4))) = f2bf(val);
                }
            }
        }
        __syncthreads();

        // phase-2 partial: acc2 += Mt[b](o, ch*256+ks) x q(n, ks)^T, K=256
        for (int ks = 0; ks < 256; ks += 32) {
            s16x8 a2[4], b2[2];
            #pragma unroll
            for (int i = 0; i < 4; ++i)
                a2[i] = *(const s16x8*)(Mb + (size_t)(wave * 64 + i * 16 + lr) * INNERc
                                        + ch * 256 + ks + quad * 8);
            #pragma unroll
            for (int j = 0; j < 2; ++j) {
                const int row = j * 16 + lr;
                b2[j] = *(const s16x8*)((char*)qlds + row * 512
                                        + ((ks * 2 + quad * 16) ^ ((row & 7) << 4)));
            }
            #pragma unroll
            for (int i = 0; i < 4; ++i)
                #pragma unroll
                for (int j = 0; j < 2; ++j)
                    acc2[i][j] = MFMA16(a2[i], b2[j], acc2[i][j]);
        }
        __syncthreads();   // qlds aliases next chunk's staging
    }

    // epilogue: out[n][o] = acc2 + bout[o]; frag rows = o (4 consecutive) -> float4
    #pragma unroll
    for (int i = 0; i < 4; ++i) {
        const int o = wave * 64 + i * 16 + quad * 4;
        float4 bv = *(const float4*)(bout + o);
        #pragma unroll
        for (int j = 0; j < 2; ++j) {
            const size_t n = (size_t)b * NN + n0 + j * 16 + lr;
            float4 v;
            v.x = acc2[i][j][0] + bv.x;
            v.y = acc2[i][j][1] + bv.y;
            v.z = acc2[i][j][2] + bv.z;
            v.w = acc2[i][j][3] + bv.w;
            *(float4*)(out + n * DIMc + o) = v;
        }
    }
}

extern "C" void kernel_launch(void* const* d_in, const int* in_sizes, int n_in,
                              void* d_out, int out_size, void* d_ws, size_t ws_size,
                              hipStream_t stream) {
    (void)in_sizes; (void)n_in; (void)out_size; (void)ws_size;
    const float* x     = (const float*)d_in[0];
    const float* z     = (const float*)d_in[1];
    const float* x_pos = (const float*)d_in[2];
    const float* z_pos = (const float*)d_in[3];
    const float* Wq    = (const float*)d_in[4];
    const float* Wkv   = (const float*)d_in[5];
    const float* Wout  = (const float*)d_in[6];
    const float* bout  = (const float*)d_in[7];
    float* out = (float*)d_out;

    char* ws = (char*)d_ws;
    us*     z_bf  = (us*)(ws + 0);                    // 16 MB
    us*     x_bf  = (us*)(ws + 16777216);             // 16 MB
    us*     WqT   = (us*)(ws + 33554432);             // 256 KB
    us*     WkvT  = (us*)(ws + 33816576);             // 512 KB
    us*     WoutT = (us*)(ws + 34340864);             // 256 KB
    float*  dots  = (float*)(ws + 34603008);          // 1 MB
    us*     Mt    = (us*)(ws + 36175872);             // 2 MB  [b][256 o][512 he]
    float4* ropeZ = (float4*)(ws + 41943040);         // 8 MB  [b*NN][16]
    float4* ropeX = (float4*)(ws + 50331648);         // 8 MB  [b*NN][16]

    prep<<<22784, 256, 0, stream>>>(x, z, x_pos, z_pos, Wq, Wkv, Wout,
                                    x_bf, z_bf, WqT, WkvT, WoutT,
                                    dots, ropeX, ropeZ);
    kvdots<<<dim3(256, 8), 512, 0, stream>>>(z_bf, ropeZ, WkvT, dots);
    mbuild<<<64, 256, 0, stream>>>(dots, WoutT, Mt);
    qout_gemm<<<1024, 256, 0, stream>>>(x_bf, ropeX, WqT, Mt, bout, out);
}

// Round 9
// 228.598 us; speedup vs baseline: 1.3427x; 1.3427x over previous
//
#include <hip/hip_runtime.h>
#include <math.h>

#define BB 8
#define NN 4096
#define DIMc 256
#define HH 8
#define DH 64
#define INNERc 512

typedef unsigned short us;
typedef short s16x8 __attribute__((ext_vector_type(8)));   // 8 bf16 operand (4 VGPRs)
typedef float f32x4 __attribute__((ext_vector_type(4)));   // 16x16 C/D frag

static __device__ __forceinline__ us f2bf(float f) {
    union { float f; unsigned int u; } c; c.f = f;
    unsigned int u = c.u;
    return (us)((u + 0x7fffu + ((u >> 16) & 1u)) >> 16);   // RNE
}

// pack 2 floats -> 2 bf16 in one instruction (RNE). lo -> bits[15:0].
static __device__ __forceinline__ unsigned int pkbf(float lo, float hi) {
    unsigned int r;
    asm("v_cvt_pk_bf16_f32 %0, %1, %2" : "=v"(r) : "v"(lo), "v"(hi));
    return r;
}

#define MFMA16(a, b, c) __builtin_amdgcn_mfma_f32_16x16x32_bf16((a), (b), (c), 0, 0, 0)

// async 16B/lane global->LDS. LDS dest must be linear: base + lane*16.
static __device__ __forceinline__ void glds16(const us* g, us* l) {
    __builtin_amdgcn_global_load_lds(
        (const __attribute__((address_space(1))) void*)g,
        (__attribute__((address_space(3))) void*)l, 16, 0, 0);
}

// ---------------------------------------------------------------
// prep: ONE dispatch for all preprocessing:
//   [0,16384)     cast z / x -> bf16
//   [16384,16896) WqT   [16896,17920) WkvT   [17920,18432) WoutT
//   [18432,18688) dots = 0
//   [18688,20736) ropeZ   [20736,22784) ropeX
// ---------------------------------------------------------------
__global__ __launch_bounds__(256) void prep(
    const float* __restrict__ x, const float* __restrict__ z,
    const float* __restrict__ x_pos, const float* __restrict__ z_pos,
    const float* __restrict__ Wq, const float* __restrict__ Wkv,
    const float* __restrict__ Wout,
    us* __restrict__ x_bf, us* __restrict__ z_bf,
    us* __restrict__ WqT, us* __restrict__ WkvT, us* __restrict__ WoutT,
    float* __restrict__ dots, float4* __restrict__ ropeX, float4* __restrict__ ropeZ)
{
    const int bid = blockIdx.x, tid = threadIdx.x;
    if (bid < 16384) {                       // cast z / x (float4 -> 4x bf16)
        const int isX = bid >= 8192;
        const int idx = (bid - (isX ? 8192 : 0)) * 256 + tid;   // < 2097152
        float4 v = ((const float4*)(isX ? x : z))[idx];
        uint2 u;
        u.x = pkbf(v.x, v.y);
        u.y = pkbf(v.z, v.w);
        ((uint2*)(isX ? x_bf : z_bf))[idx] = u;
    } else if (bid < 16896) {                // WqT
        const int idx = (bid - 16384) * 256 + tid;   // < 131072
        const int r = idx >> 8, c = idx & 255;
        WqT[idx] = f2bf(Wq[(size_t)c * 512 + r]);
    } else if (bid < 17920) {                // WkvT
        const int idx = (bid - 16896) * 256 + tid;   // < 262144
        const int r = idx >> 8, c = idx & 255;
        WkvT[idx] = f2bf(Wkv[(size_t)c * 1024 + r]);
    } else if (bid < 18432) {                // WoutT
        const int idx = (bid - 17920) * 256 + tid;   // < 131072
        const int r = idx >> 9, c = idx & 511;
        WoutT[idx] = f2bf(Wout[(size_t)c * 256 + r]);
    } else if (bid < 18688) {                // dots = 0 (65536 float4)
        const int idx = (bid - 18432) * 256 + tid;
        ((float4*)dots)[idx] = float4{0.f, 0.f, 0.f, 0.f};
    } else {                                 // rope tables
        const int isZ = bid < 20736;
        const int idx = (bid - (isZ ? 18688 : 20736)) * 256 + tid;  // < 524288
        const int f = idx & 15, row = idx >> 4;                     // row = b*NN+n
        float invf = exp2f((float)f * -0.83048202f);   // 10000^(-f/16)
        const float* p = (isZ ? z_pos : x_pos) + (size_t)row * 2;
        float sx, cx, sy, cy;
        sincosf(p[0] * 64.f * invf, &sx, &cx);
        sincosf(p[1] * 64.f * invf, &sy, &cy);
        (isZ ? ropeZ : ropeX)[idx] = float4{cx, sx, cy, sy};
    }
}

// ---------------------------------------------------------------
// kvdots: fused. Per block (b, ntile, h):
//   GEMM 128n x [K_h(64) | V_h(64)] cols, K=256 (global_load_lds staging,
//   XOR-swizzled LDS) -> in-reg instance-norm + rotary(K, table from ropeZ)
//   -> K,V to LDS [64][128n] swizzled -> dots_h partial -> fp32 atomics.
// grid (x: b*32+ntile = 256, y: h = 8), 512 threads (8 waves).
// ---------------------------------------------------------------
__global__ __launch_bounds__(512) void kvdots(
    const us* __restrict__ zbf, const float4* __restrict__ ropeZ,
    const us* __restrict__ WkvT, float* __restrict__ dots)
{
    __shared__ __align__(16) char smem[65536];
    us* Abuf = (us*)smem;               // [128][64] us, swizzled granules (16KB)
    us* Bbuf = (us*)(smem + 16384);     // [128][64] us (16KB)
    us* Kl = (us*)(smem + 32768);       // [64 d][128 n] us, swizzled (16KB)
    us* Vl = (us*)(smem + 49152);       // [64 e][128 n] us, swizzled (16KB)

    const int tid = threadIdx.x;
    const int b  = blockIdx.x >> 5;
    const int r0 = (blockIdx.x & 31) * 128;
    const int h  = blockIdx.y;

    const int wave = tid >> 6, lane = tid & 63;
    const int lr = lane & 15, quad = lane >> 4;
    const int wrow = wave & 3;          // 32-row block of the 128 n rows
    const int wc   = wave >> 2;         // 0: K half, 1: V half

    const us* Asrc = zbf + ((size_t)b * NN + r0) * DIMc;
    const float4* rz = ropeZ + ((size_t)b * NN + r0) * 16;

    const int srow = lane >> 3;
    const int sq   = (lane & 7) ^ srow;

    f32x4 z4 = {0.f, 0.f, 0.f, 0.f};
    f32x4 acc[2][4];
    #pragma unroll
    for (int i = 0; i < 2; ++i)
        #pragma unroll
        for (int j = 0; j < 4; ++j) acc[i][j] = z4;

    for (int kc = 0; kc < 256; kc += 64) {
        #pragma unroll
        for (int k = 0; k < 4; ++k) {
            const int c = wave * 4 + k;          // 0..31: 16 A chunks, 16 B chunks
            if (c < 16) {
                const int row = c * 8 + srow;
                glds16(Asrc + (size_t)row * DIMc + kc + sq * 8,
                       Abuf + c * 512 + lane * 8);
            } else {
                const int brow = (c - 16) * 8 + srow;      // 0..127
                const int wrg = h * 64 + brow + ((brow & 64) ? 448 : 0);
                glds16(WkvT + (size_t)wrg * DIMc + kc + sq * 8,
                       Bbuf + (c - 16) * 512 + lane * 8);
            }
        }
        __syncthreads();
        #pragma unroll
        for (int ks = 0; ks < 64; ks += 32) {
            const int qb = (ks >> 3) + quad;     // logical granule wanted
            s16x8 a[2], bfr[4];
            #pragma unroll
            for (int i = 0; i < 2; ++i) {
                const int row = wrow * 32 + i * 16 + lr;
                a[i] = *(const s16x8*)(Abuf + row * 64 + ((qb ^ (row & 7)) << 3));
            }
            #pragma unroll
            for (int j = 0; j < 4; ++j) {
                const int brow = wc * 64 + j * 16 + lr;
                bfr[j] = *(const s16x8*)(Bbuf + brow * 64 + ((qb ^ (brow & 7)) << 3));
            }
            #pragma unroll
            for (int i = 0; i < 2; ++i)
                #pragma unroll
                for (int j = 0; j < 4; ++j)
                    acc[i][j] = MFMA16(a[i], bfr[j], acc[i][j]);
        }
        __syncthreads();
    }

    // epilogue: norm (+rotary for K from ropeZ) in regs -> Kl/Vl [64][128] swizzled
    us* KVl = wc ? Vl : Kl;
    #pragma unroll
    for (int i = 0; i < 2; ++i) {
        float mu_[4], rs_[4];
        #pragma unroll
        for (int r = 0; r < 4; ++r) {
            float s = acc[i][0][r] + acc[i][1][r] + acc[i][2][r] + acc[i][3][r];
            float q2 = acc[i][0][r] * acc[i][0][r] + acc[i][1][r] * acc[i][1][r]
                     + acc[i][2][r] * acc[i][2][r] + acc[i][3][r] * acc[i][3][r];
            s += __shfl_xor(s, 1);  q2 += __shfl_xor(q2, 1);
            s += __shfl_xor(s, 2);  q2 += __shfl_xor(q2, 2);
            s += __shfl_xor(s, 4);  q2 += __shfl_xor(q2, 4);
            s += __shfl_xor(s, 8);  q2 += __shfl_xor(q2, 8);
            float mu = s * (1.f / 64.f);
            float var = q2 * (1.f / 64.f) - mu * mu;
            mu_[r] = mu;
            rs_[r] = rsqrtf(var + 1e-5f);
        }
        float4 tb[4];
        if (wc == 0) {
            #pragma unroll
            for (int r = 0; r < 4; ++r)
                tb[r] = rz[(wrow * 32 + i * 16 + quad * 4 + r) * 16 + lr];
        }
        #pragma unroll
        for (int j = 0; j < 4; ++j) {
            float vv[4];
            #pragma unroll
            for (int r = 0; r < 4; ++r) {
                float v0 = (acc[i][j][r] - mu_[r]) * rs_[r];
                if (wc == 0) {
                    float v1 = (acc[i][j ^ 1][r] - mu_[r]) * rs_[r];
                    float cc = (j < 2) ? tb[r].x : tb[r].z;
                    float sn = (j < 2) ? tb[r].y : tb[r].w;
                    v0 = (j & 1) ? fmaf(v0, cc, v1 * sn) : fmaf(v0, cc, -(v1 * sn));
                }
                vv[r] = v0;
            }
            uint2 pk;
            pk.x = pkbf(vv[0], vv[1]);
            pk.y = pkbf(vv[2], vv[3]);
            const int d = j * 16 + lr;
            const int n = wrow * 32 + i * 16 + quad * 4;   // 4-aligned
            const int g = n >> 3, hs = (n >> 2) & 1;       // 16B granule, 8B half
            *(uint2*)((char*)KVl + d * 256 + ((g ^ (d & 15)) << 4) + hs * 8) = pk;
        }
    }
    __syncthreads();

    // dots_h partial: dots[d][e] += sum_{n in tile} K[n,d] * V[n,e]
    const int d0 = (wave & 3) * 16, e0 = (wave >> 2) * 32;
    f32x4 c2[2] = {z4, z4};
    #pragma unroll
    for (int kk = 0; kk < 128; kk += 32) {
        const int qg = (kk >> 3) + quad;
        const int da = d0 + lr;
        s16x8 a = *(const s16x8*)(Kl + da * 128 + ((qg ^ (da & 15)) << 3));
        #pragma unroll
        for (int j = 0; j < 2; ++j) {
            const int e = e0 + j * 16 + lr;
            s16x8 bb = *(const s16x8*)(Vl + e * 128 + ((qg ^ (e & 15)) << 3));
            c2[j] = MFMA16(a, bb, c2[j]);
        }
    }
    float* dp = dots + ((size_t)b * HH + h) * (DH * DH);
    #pragma unroll
    for (int j = 0; j < 2; ++j)
        #pragma unroll
        for (int r = 0; r < 4; ++r)
            atomicAdd(dp + (d0 + quad * 4 + r) * 64 + e0 + j * 16 + lr, c2[j][r]);
}

// ---------------------------------------------------------------
// mbuild: Mt[b][o][h*64+d] = sum_e dots[b,h][d][e]/N * WoutT[o][h*64+e]
// grid: 64 blocks = (b,h); 256 threads (4 waves, each 64 o-rows).
// ---------------------------------------------------------------
__global__ __launch_bounds__(256) void mbuild(
    const float* __restrict__ dots, const us* __restrict__ WoutT,
    us* __restrict__ Mt)
{
    __shared__ __align__(16) us dlds[64 * 72];   // dots_h bf16, row d, padded
    const int bh = blockIdx.x;
    const int b = bh >> 3, h = bh & 7;
    const int tid = threadIdx.x;

    for (int i = tid; i < 4096; i += 256) {
        int d = i >> 6, e = i & 63;
        dlds[d * 72 + e] = f2bf(dots[(size_t)bh * 4096 + i] * (1.f / (float)NN));
    }
    __syncthreads();

    const int wave = tid >> 6, lane = tid & 63;
    const int lr = lane & 15, quad = lane >> 4;
    const int o0 = wave * 64;

    f32x4 z4 = {0.f, 0.f, 0.f, 0.f};
    f32x4 c[4][4];
    #pragma unroll
    for (int i = 0; i < 4; ++i)
        #pragma unroll
        for (int j = 0; j < 4; ++j) c[i][j] = z4;

    #pragma unroll
    for (int ks = 0; ks < 64; ks += 32) {
        s16x8 a[4], bfr[4];
        #pragma unroll
        for (int i = 0; i < 4; ++i)
            a[i] = *(const s16x8*)(WoutT + (size_t)(o0 + i * 16 + lr) * INNERc + h * 64 + ks + quad * 8);
        #pragma unroll
        for (int j = 0; j < 4; ++j)
            bfr[j] = *(const s16x8*)(dlds + (j * 16 + lr) * 72 + ks + quad * 8);
        #pragma unroll
        for (int i = 0; i < 4; ++i)
            #pragma unroll
            for (int j = 0; j < 4; ++j)
                c[i][j] = MFMA16(a[i], bfr[j], c[i][j]);
    }

    us* Mb = Mt + (size_t)b * (DIMc * INNERc);   // [256 o][512 he]
    #pragma unroll
    for (int i = 0; i < 4; ++i)
        #pragma unroll
        for (int j = 0; j < 4; ++j) {
            const int d = j * 16 + lr;
            #pragma unroll
            for (int r = 0; r < 4; ++r)
                Mb[(size_t)(o0 + i * 16 + quad * 4 + r) * INNERc + h * 64 + d] = f2bf(c[i][j][r]);
        }
}

// ---------------------------------------------------------------
// qout_gemm v5: 32-row n-tiles, 256 threads (4 waves), grid 1024.
// NO min-waves cap (v4's __launch_bounds__(256,4) caused scratch spills:
// WRITE_SIZE 34->212 MB, VGPR 220->64). Compiler-chosen VGPR -> ~3 blocks/CU.
// Bijective XCD swizzle: each XCD's 128 blocks share one b -> its L2 holds
// one Mt[b] (256 KB) + WqT (512 KB).
// Per chunk ch: q = x@Wq (32n x 256he, K=256) via glds16 (XOR-swizzled) ->
// rotary (ropeX) -> qlds [32][256] swizzled -> acc2 += Mt[b][:,chunk] x q^T.
// LDS: staging A 4K + B 32K (qlds 16K aliases) = 36864 B.
// ---------------------------------------------------------------
__global__ __launch_bounds__(256) void qout_gemm(
    const us* __restrict__ xbf, const float4* __restrict__ ropeX,
    const us* __restrict__ WqT, const us* __restrict__ Mt,
    const float* __restrict__ bout, float* __restrict__ out)
{
    __shared__ __align__(16) char smem[36864];
    us* Abuf = (us*)smem;                    // [32][64] granule-swizzled (4 KB)
    us* Bbuf = (us*)(smem + 4096);           // [256][64] granule-swizzled (32 KB)
    us* qlds = (us*)smem;                    // alias: [32 n][256 he] swizzled (16 KB)

    const int tid = threadIdx.x;
    // bijective XCD swizzle (nwg=1024, 8 XCDs, 128 blocks each, same b per XCD)
    const int swz = (blockIdx.x & 7) * 128 + (blockIdx.x >> 3);
    const int b  = swz >> 7;
    const int n0 = (swz & 127) * 32;
    const int wave = tid >> 6, lane = tid & 63;
    const int lr = lane & 15, quad = lane >> 4;
    const int srow = lane >> 3;
    const int sq   = (lane & 7) ^ srow;

    const us* Asrc = xbf + ((size_t)b * NN + n0) * DIMc;
    const float4* rx = ropeX + ((size_t)b * NN + n0) * 16;
    const us* Mb = Mt + (size_t)b * (DIMc * INNERc);

    f32x4 z4 = {0.f, 0.f, 0.f, 0.f};
    f32x4 acc2[4][2];                        // [o-frag][n-frag]
    #pragma unroll
    for (int i = 0; i < 4; ++i)
        #pragma unroll
        for (int j = 0; j < 2; ++j) acc2[i][j] = z4;

    for (int ch = 0; ch < 2; ++ch) {
        f32x4 acc[2][4];                     // [n-frag][he-frag]
        #pragma unroll
        for (int i = 0; i < 2; ++i)
            #pragma unroll
            for (int j = 0; j < 4; ++j) acc[i][j] = z4;

        for (int kc = 0; kc < 256; kc += 64) {
            // 36 chunks of 1024B (A: 4, B: 32), 9 per wave
            #pragma unroll
            for (int k = 0; k < 9; ++k) {
                const int c = wave * 9 + k;
                if (c < 4) {
                    const int row = c * 8 + srow;
                    glds16(Asrc + (size_t)row * DIMc + kc + sq * 8,
                           Abuf + c * 512 + lane * 8);
                } else {
                    const int cb = c - 4;
                    const int grow = ch * 256 + cb * 8 + srow;
                    glds16(WqT + (size_t)grow * DIMc + kc + sq * 8,
                           Bbuf + cb * 512 + lane * 8);
                }
            }
            __syncthreads();
            #pragma unroll
            for (int ks = 0; ks < 64; ks += 32) {
                const int qb = (ks >> 3) + quad;
                s16x8 a[2], bfr[4];
                #pragma unroll
                for (int i = 0; i < 2; ++i) {
                    const int row = i * 16 + lr;
                    a[i] = *(const s16x8*)(Abuf + row * 64 + ((qb ^ (row & 7)) << 3));
                }
                #pragma unroll
                for (int j = 0; j < 4; ++j) {
                    const int brow = wave * 64 + j * 16 + lr;
                    bfr[j] = *(const s16x8*)(Bbuf + brow * 64 + ((qb ^ (brow & 7)) << 3));
                }
                #pragma unroll
                for (int i = 0; i < 2; ++i)
                    #pragma unroll
                    for (int j = 0; j < 4; ++j)
                        acc[i][j] = MFMA16(a[i], bfr[j], acc[i][j]);
            }
            __syncthreads();
        }

        // rotary in regs (table from ropeX) -> qlds [32][256] swizzled
        #pragma unroll
        for (int i = 0; i < 2; ++i) {
            float4 tb[4];
            #pragma unroll
            for (int r = 0; r < 4; ++r)
                tb[r] = rx[(i * 16 + quad * 4 + r) * 16 + lr];
            #pragma unroll
            for (int j = 0; j < 4; ++j) {
                const int col = wave * 64 + j * 16 + lr;
                #pragma unroll
                for (int r = 0; r < 4; ++r) {
                    const int row = i * 16 + quad * 4 + r;
                    float v0 = acc[i][j][r];
                    float v1 = acc[i][j ^ 1][r];
                    float cc = (j < 2) ? tb[r].x : tb[r].z;
                    float sn = (j < 2) ? tb[r].y : tb[r].w;
                    float val = (j & 1) ? fmaf(v0, cc, v1 * sn) : fmaf(v0, cc, -(v1 * sn));
                    *(us*)((char*)qlds + row * 512 + ((col * 2) ^ ((row & 7) << 4))) = f2bf(val);
                }
            }
        }
        __syncthreads();

        // phase-2 partial: acc2 += Mt[b](o, ch*256+ks) x q(n, ks)^T, K=256
        for (int ks = 0; ks < 256; ks += 32) {
            s16x8 a2[4], b2[2];
            #pragma unroll
            for (int i = 0; i < 4; ++i)
                a2[i] = *(const s16x8*)(Mb + (size_t)(wave * 64 + i * 16 + lr) * INNERc
                                        + ch * 256 + ks + quad * 8);
            #pragma unroll
            for (int j = 0; j < 2; ++j) {
                const int row = j * 16 + lr;
                b2[j] = *(const s16x8*)((char*)qlds + row * 512
                                        + ((ks * 2 + quad * 16) ^ ((row & 7) << 4)));
            }
            #pragma unroll
            for (int i = 0; i < 4; ++i)
                #pragma unroll
                for (int j = 0; j < 2; ++j)
                    acc2[i][j] = MFMA16(a2[i], b2[j], acc2[i][j]);
        }
        __syncthreads();   // qlds aliases next chunk's staging
    }

    // epilogue: out[n][o] = acc2 + bout[o]; frag rows = o (4 consecutive) -> float4
    #pragma unroll
    for (int i = 0; i < 4; ++i) {
        const int o = wave * 64 + i * 16 + quad * 4;
        float4 bv = *(const float4*)(bout + o);
        #pragma unroll
        for (int j = 0; j < 2; ++j) {
            const size_t n = (size_t)b * NN + n0 + j * 16 + lr;
            float4 v;
            v.x = acc2[i][j][0] + bv.x;
            v.y = acc2[i][j][1] + bv.y;
            v.z = acc2[i][j][2] + bv.z;
            v.w = acc2[i][j][3] + bv.w;
            *(float4*)(out + n * DIMc + o) = v;
        }
    }
}

extern "C" void kernel_launch(void* const* d_in, const int* in_sizes, int n_in,
                              void* d_out, int out_size, void* d_ws, size_t ws_size,
                              hipStream_t stream) {
    (void)in_sizes; (void)n_in; (void)out_size; (void)ws_size;
    const float* x     = (const float*)d_in[0];
    const float* z     = (const float*)d_in[1];
    const float* x_pos = (const float*)d_in[2];
    const float* z_pos = (const float*)d_in[3];
    const float* Wq    = (const float*)d_in[4];
    const float* Wkv   = (const float*)d_in[5];
    const float* Wout  = (const float*)d_in[6];
    const float* bout  = (const float*)d_in[7];
    float* out = (float*)d_out;

    char* ws = (char*)d_ws;
    us*     z_bf  = (us*)(ws + 0);                    // 16 MB
    us*     x_bf  = (us*)(ws + 16777216);             // 16 MB
    us*     WqT   = (us*)(ws + 33554432);             // 256 KB
    us*     WkvT  = (us*)(ws + 33816576);             // 512 KB
    us*     WoutT = (us*)(ws + 34340864);             // 256 KB
    float*  dots  = (float*)(ws + 34603008);          // 1 MB
    us*     Mt    = (us*)(ws + 36175872);             // 2 MB  [b][256 o][512 he]
    float4* ropeZ = (float4*)(ws + 41943040);         // 8 MB  [b*NN][16]
    float4* ropeX = (float4*)(ws + 50331648);         // 8 MB  [b*NN][16]

    prep<<<22784, 256, 0, stream>>>(x, z, x_pos, z_pos, Wq, Wkv, Wout,
                                    x_bf, z_bf, WqT, WkvT, WoutT,
                                    dots, ropeX, ropeZ);
    kvdots<<<dim3(256, 8), 512, 0, stream>>>(z_bf, ropeZ, WkvT, dots);
    mbuild<<<64, 256, 0, stream>>>(dots, WoutT, Mt);
    qout_gemm<<<1024, 256, 0, stream>>>(x_bf, ropeX, WqT, Mt, bout, out);
}